// Round 4
// baseline (300.246 us; speedup 1.0000x reference)
//
#include <hip/hip_runtime.h>
#include <math.h>
#include <stdint.h>

#define TOPK 8
#define NEXP 256

// ---------- exact-path helpers (fallback only) ----------
__device__ __forceinline__ uint32_t fmap(float v) {
  uint32_t b = __float_as_uint(v);
  uint32_t m = (uint32_t)((int32_t)b >> 31) | 0x80000000u;
  return b ^ m;
}
__device__ __forceinline__ float funmap(uint32_t k) {
  uint32_t b = (k & 0x80000000u) ? (k ^ 0x80000000u) : ~k;
  return __uint_as_float(b);
}

// ---------- fast-path fixed-point packed keys ----------
// swb = sigmoid(x)+bias ∈ roughly (-4,5) ⊂ (-8,8).
// u = trunc((swb+8)*2^20) ∈ (0,2^24): monotone, resolution 2^-20.
// packed = (u<<8) | (255-idx): descending = score desc, ties -> smaller idx
// (exactly jax top_k semantics).
__device__ __forceinline__ float unpack_swb(uint32_t p) {
  return fmaf((float)(p >> 8), 9.5367431640625e-07f, -8.0f);
}

// bubble-down insert into sorted-descending Karr[8]; pure umax/umin, no cndmask.
// r9 accumulates max displaced value.
#define PINSERT(Karr, pp)                               \
  { uint32_t _c = (pp);                                 \
    _Pragma("unroll")                                   \
    for (int _s = 0; _s < TOPK; ++_s) {                 \
      const uint32_t _o = Karr[_s];                     \
      const uint32_t _hi = _o > _c ? _o : _c;           \
      const uint32_t _lo = _o > _c ? _c : _o;           \
      Karr[_s] = _hi; _c = _lo;                         \
    }                                                   \
    r9 = r9 > _c ? r9 : _c; }

// sigmoid + bias -> packed key. rcp is ~1ulp on gfx9+, no NR needed:
// total fast-path error ~5e-7 + 9.5e-7 quantization, guarded by 6e-6 gap check.
#define PKEY(sv, bv, ci)                                                  \
  ({ const float _e = __expf(-(sv));                                      \
     const float _iv = __builtin_amdgcn_rcpf(1.0f + _e);                  \
     const float _swb = _iv + (bv);                                       \
     const uint32_t _u = (uint32_t)fmaf(_swb, 1048576.0f, 8388608.0f);    \
     (_u << 8) | (uint32_t)(255 - (ci)); })

// compare-exchange (descending) on array M, single-u32 keys: umax+umin
#define CE(i, j) { const uint32_t _a = M[i], _b = M[j];                   \
                   M[i] = _a > _b ? _a : _b; M[j] = _a > _b ? _b : _a; }
#define SORT8_BITONIC()                                                   \
  CE(0,4) CE(1,5) CE(2,6) CE(3,7)                                         \
  CE(0,2) CE(1,3) CE(4,6) CE(5,7)                                         \
  CE(0,1) CE(2,3) CE(4,5) CE(6,7)

__global__ __launch_bounds__(256, 4)
void moe_route_kernel(const float* __restrict__ logits,
                      const float* __restrict__ bias,
                      float* __restrict__ out_idx,
                      float* __restrict__ out_w,
                      int T)
{
  const int tid  = threadIdx.x;
  const int lane = tid & 63;
  const int q    = lane & 3;                      // 4 lanes per row
  const int grow = blockIdx.x * 64 + (tid >> 2);
  const int rrow = grow < T ? grow : (T - 1);     // clamp: whole wave stays active

  const float4* __restrict__ rowp4 = (const float4*)(logits + (size_t)rrow * NEXP);
  const float4* __restrict__ bias4 = (const float4*)bias;

  // issue all 16 owned float4 loads up-front (quad covers full 64B lines)
  float4 x[16];
#pragma unroll
  for (int k = 0; k < 16; ++k) x[k] = rowp4[q + 4 * k];

  // dual independent cascades (even/odd elements) -> 2x chain ILP
  uint32_t A[TOPK], B[TOPK];
#pragma unroll
  for (int i = 0; i < TOPK; ++i) { A[i] = 0u; B[i] = 0u; }
  uint32_t r9 = 0u;

#pragma unroll
  for (int k = 0; k < 16; ++k) {
    const float4 bb = bias4[q + 4 * k];           // 1KB, L1-hot
    const int cb = 4 * q + 16 * k;
    const uint32_t p0 = PKEY(x[k].x, bb.x, cb + 0);
    const uint32_t p1 = PKEY(x[k].y, bb.y, cb + 1);
    const uint32_t p2 = PKEY(x[k].z, bb.z, cb + 2);
    const uint32_t p3 = PKEY(x[k].w, bb.w, cb + 3);
    PINSERT(A, p0); PINSERT(B, p1);
    PINSERT(A, p2); PINSERT(B, p3);
  }

  // ---- merge B into A -> M = sorted top-8 of lane's 64, track displaced ----
  uint32_t M[TOPK];
  {
    uint32_t dmax = 0u;
#pragma unroll
    for (int i = 0; i < TOPK; ++i) {
      const uint32_t a = A[i], b = B[TOPK - 1 - i];
      M[i] = a > b ? a : b;
      const uint32_t d = a > b ? b : a;
      dmax = dmax > d ? dmax : d;
    }
    r9 = r9 > dmax ? r9 : dmax;
    SORT8_BITONIC()
  }

  // ---- two xor-shuffle merges across the quad (result replicated) ----
#pragma unroll
  for (int mstep = 0; mstep < 2; ++mstep) {
    const int mask = 1 << mstep;
    uint32_t P[TOPK];
#pragma unroll
    for (int i = 0; i < TOPK; ++i)
      P[i] = (uint32_t)__shfl_xor((int)M[i], mask, 64);
    const uint32_t r9p = (uint32_t)__shfl_xor((int)r9, mask, 64);
    r9 = r9 > r9p ? r9 : r9p;
    uint32_t dmax = 0u;
#pragma unroll
    for (int i = 0; i < TOPK; ++i) {
      const uint32_t a = M[i], b = P[TOPK - 1 - i];
      const uint32_t hi = a > b ? a : b;
      const uint32_t d  = a > b ? b : a;
      M[i] = hi;
      dmax = dmax > d ? dmax : d;
    }
    r9 = r9 > dmax ? r9 : dmax;
    SORT8_BITONIC()
  }

  // ---- ambiguity: min adjacent gap over recovered swb (top-8 + 9th) ----
  float prev = unpack_swb(M[0]);
  float ming = 1e30f;
#pragma unroll
  for (int i = 1; i < TOPK; ++i) {
    const float vi = unpack_swb(M[i]);
    ming = fminf(ming, prev - vi);
    prev = vi;
  }
  ming = fminf(ming, prev - unpack_swb(r9));

  // ---- leader produces outputs (rarely after an exact f64 redo) ----
  if (grow < T && q == 0) {
    float sw[TOPK]; int id8[TOPK];
#pragma unroll
    for (int i = 0; i < TOPK; ++i) {
      sw[i]  = unpack_swb(M[i]);
      id8[i] = 255 - (int)(M[i] & 255u);
    }
    if (ming < 6e-6f) {               // ~3e-4 of rows: exact rescan
      uint32_t K[TOPK], I[TOPK];
#pragma unroll
      for (int i = 0; i < TOPK; ++i) { K[i] = 0u; I[i] = 0u; }
      const float* rowp = logits + (size_t)grow * NEXP;
      for (int c = 0; c < NEXP; ++c) {
        const double sd = 1.0 / (1.0 + exp(-(double)rowp[c]));
        const float swb = (float)sd + bias[c];
        uint32_t k2 = fmap(swb); uint32_t i2 = (uint32_t)c;
#pragma unroll
        for (int s = 0; s < TOPK; ++s) {
          const bool t = k2 > K[s];
          const uint32_t ok = K[s], oi = I[s];
          K[s] = t ? k2 : ok; I[s] = t ? i2 : oi;
          k2 = t ? ok : k2; i2 = t ? oi : i2;
        }
      }
#pragma unroll
      for (int i = 0; i < TOPK; ++i) { sw[i] = funmap(K[i]); id8[i] = (int)I[i]; }
    }
    // unbiased sigmoid back out, normalize, store
    float s[TOPK]; float sum = 0.f;
#pragma unroll
    for (int i = 0; i < TOPK; ++i) { s[i] = sw[i] - bias[id8[i]]; sum += s[i]; }
    const float innv = 1.0f / (sum + 1e-20f);
    float* const po = out_idx + (size_t)grow * 8;
    float* const pw = out_w   + (size_t)grow * 8;
    *(float4*)(po)     = make_float4((float)id8[0], (float)id8[1], (float)id8[2], (float)id8[3]);
    *(float4*)(po + 4) = make_float4((float)id8[4], (float)id8[5], (float)id8[6], (float)id8[7]);
    *(float4*)(pw)     = make_float4(s[0]*innv, s[1]*innv, s[2]*innv, s[3]*innv);
    *(float4*)(pw + 4) = make_float4(s[4]*innv, s[5]*innv, s[6]*innv, s[7]*innv);
  }
}

extern "C" void kernel_launch(void* const* d_in, const int* in_sizes, int n_in,
                              void* d_out, int out_size, void* d_ws, size_t ws_size,
                              hipStream_t stream) {
  const float* logits = (const float*)d_in[0];
  const float* bias   = (const float*)d_in[1];
  const int T = in_sizes[0] / NEXP;
  float* out     = (float*)d_out;
  float* out_idx = out;
  float* out_w   = out + (size_t)T * TOPK;
  const int blocks = (T + 63) / 64;
  moe_route_kernel<<<blocks, 256, 0, stream>>>(logits, bias, out_idx, out_w, T);
}

// Round 7
// 294.403 us; speedup vs baseline: 1.0198x; 1.0198x over previous
//
#include <hip/hip_runtime.h>
#include <math.h>
#include <stdint.h>
#include <utility>

#define TOPK 8
#define NEXP 256
#define DEPTH 4   // DMAs in flight per wave
#define NSLOT 5   // ring slots = DEPTH+1: in-flight DMAs never alias the read slot

// ---------- compile-time for: makes loop index constexpr at each call ----------
template <typename F, int... Is>
__device__ __forceinline__ void static_for_impl(F&& f, std::integer_sequence<int, Is...>) {
  int dummy[] = {0, ((void)f(std::integral_constant<int, Is>{}), 0)...};
  (void)dummy;
}
template <int N, typename F>
__device__ __forceinline__ void static_for(F&& f) {
  static_for_impl((F&&)f, std::make_integer_sequence<int, N>{});
}

// ---------- exact-path helpers (fallback only) ----------
__device__ __forceinline__ uint32_t fmap(float v) {
  uint32_t b = __float_as_uint(v);
  uint32_t m = (uint32_t)((int32_t)b >> 31) | 0x80000000u;
  return b ^ m;
}
__device__ __forceinline__ float funmap(uint32_t k) {
  uint32_t b = (k & 0x80000000u) ? (k ^ 0x80000000u) : ~k;
  return __uint_as_float(b);
}

// ---------- fast-path fixed-point packed keys (proven R4) ----------
// u = trunc((swb+8)*2^20) ∈ (0,2^24), monotone; packed=(u<<8)|(255-idx):
// descending order = score desc, ties -> smaller idx (jax top_k semantics).
__device__ __forceinline__ float unpack_swb(uint32_t p) {
  return fmaf((float)(p >> 8), 9.5367431640625e-07f, -8.0f);
}

#define PINSERT(Karr, pp)                               \
  { uint32_t _c = (pp);                                 \
    _Pragma("unroll")                                   \
    for (int _s = 0; _s < TOPK; ++_s) {                 \
      const uint32_t _o = Karr[_s];                     \
      const uint32_t _hi = _o > _c ? _o : _c;           \
      const uint32_t _lo = _o > _c ? _c : _o;           \
      Karr[_s] = _hi; _c = _lo;                         \
    }                                                   \
    r9 = r9 > _c ? r9 : _c; }

#define PKEY(sv, bv, ci)                                                  \
  ({ const float _e = __expf(-(sv));                                      \
     const float _iv = __builtin_amdgcn_rcpf(1.0f + _e);                  \
     const float _swb = _iv + (bv);                                       \
     const uint32_t _u = (uint32_t)fmaf(_swb, 1048576.0f, 8388608.0f);    \
     (_u << 8) | (uint32_t)(255 - (ci)); })

#define CE(i, j) { const uint32_t _a = M[i], _b = M[j];                   \
                   M[i] = _a > _b ? _a : _b; M[j] = _a > _b ? _b : _a; }
#define SORT8_BITONIC()                                                   \
  CE(0,4) CE(1,5) CE(2,6) CE(3,7)                                         \
  CE(0,2) CE(1,3) CE(4,6) CE(5,7)                                         \
  CE(0,1) CE(2,3) CE(4,5) CE(6,7)

// issue one 16B/lane direct-to-LDS DMA; lds base wave-uniform, HW adds lane*16
__device__ __forceinline__ void prefetch_lds(const char* g, char* l) {
  __builtin_amdgcn_global_load_lds(
      (const __attribute__((address_space(1))) void*)g,
      (__attribute__((address_space(3))) void*)l, 16, 0, 0);
}

__global__ __launch_bounds__(256, 8)
void moe_route_kernel(const float* __restrict__ logits,
                      const float* __restrict__ bias,
                      float* __restrict__ out_idx,
                      float* __restrict__ out_w,
                      int T)
{
  __shared__ float biasLDS[NEXP];            // 1KB
  __shared__ char  ring[4][NSLOT * 1024];    // 20KB: private 5KB ring per wave

  const int tid  = threadIdx.x;
  const int lane = tid & 63;
  const int wave = tid >> 6;
  const int q    = lane & 3;                      // 4 lanes per row
  const int grow = blockIdx.x * 64 + (tid >> 2);
  const int rrow = grow < T ? grow : (T - 1);     // clamp: whole wave active

  if (tid < NEXP) biasLDS[tid] = bias[tid];
  __syncthreads();                                // once, before any prefetch

  // lane's chunk-0 address; successive steps advance 64B (chunks q+4k)
  const char* gbase = (const char*)(logits + (size_t)rrow * NEXP) + q * 16;
  char* ringw = ring[wave];                       // wave-uniform

  // ---- prologue: fill DEPTH slots ----
#pragma unroll
  for (int k = 0; k < DEPTH; ++k)
    prefetch_lds(gbase + (size_t)k * 64, ringw + (k % NSLOT) * 1024);

  uint32_t A[TOPK], B[TOPK];
#pragma unroll
  for (int i = 0; i < TOPK; ++i) { A[i] = 0u; B[i] = 0u; }
  uint32_t r9 = 0u;

  // ---- steady state: issue k+DEPTH into slot (k+DEPTH)%5 (never the slot
  // being read, k%5), wait vmcnt(outstanding), consume slot k%5 ----
  static_for<16>([&](auto kc) {
    constexpr int k = decltype(kc)::value;
    if (k + DEPTH < 16)
      prefetch_lds(gbase + (size_t)(k + DEPTH) * 64,
                   ringw + ((k + DEPTH) % NSLOT) * 1024);
    constexpr int nwait = (k + DEPTH < 16) ? DEPTH : (15 - k);
    // gfx9 encoding: vmcnt low nibble, expcnt=7 (no wait), lgkmcnt=15 (no wait)
    __builtin_amdgcn_s_waitcnt(0x0F70 | nwait);

    const float4 x  = *(const float4*)(ringw + (k % NSLOT) * 1024 + lane * 16);
    const float4 bb = ((const float4*)biasLDS)[q + 4 * k];  // broadcast ds_read
    const int cb = 4 * q + 16 * k;
    const uint32_t p0 = PKEY(x.x, bb.x, cb + 0);
    const uint32_t p1 = PKEY(x.y, bb.y, cb + 1);
    const uint32_t p2 = PKEY(x.z, bb.z, cb + 2);
    const uint32_t p3 = PKEY(x.w, bb.w, cb + 3);
    PINSERT(A, p0); PINSERT(B, p1);
    PINSERT(A, p2); PINSERT(B, p3);
  });

  // ---- merge B into A -> M = lane's sorted top-8, track displaced ----
  uint32_t M[TOPK];
  {
    uint32_t dmax = 0u;
#pragma unroll
    for (int i = 0; i < TOPK; ++i) {
      const uint32_t a = A[i], b = B[TOPK - 1 - i];
      M[i] = a > b ? a : b;
      const uint32_t d = a > b ? b : a;
      dmax = dmax > d ? dmax : d;
    }
    r9 = r9 > dmax ? r9 : dmax;
    SORT8_BITONIC()
  }

  // ---- two xor-shuffle merges across the quad (result replicated) ----
#pragma unroll
  for (int mstep = 0; mstep < 2; ++mstep) {
    const int mask = 1 << mstep;
    uint32_t P[TOPK];
#pragma unroll
    for (int i = 0; i < TOPK; ++i)
      P[i] = (uint32_t)__shfl_xor((int)M[i], mask, 64);
    const uint32_t r9p = (uint32_t)__shfl_xor((int)r9, mask, 64);
    r9 = r9 > r9p ? r9 : r9p;
    uint32_t dmax = 0u;
#pragma unroll
    for (int i = 0; i < TOPK; ++i) {
      const uint32_t a = M[i], b = P[TOPK - 1 - i];
      const uint32_t hi = a > b ? a : b;
      const uint32_t d  = a > b ? b : a;
      M[i] = hi;
      dmax = dmax > d ? dmax : d;
    }
    r9 = r9 > dmax ? r9 : dmax;
    SORT8_BITONIC()
  }

  // ---- ambiguity: min adjacent gap over recovered swb (top-8 + 9th) ----
  float prev = unpack_swb(M[0]);
  float ming = 1e30f;
#pragma unroll
  for (int i = 1; i < TOPK; ++i) {
    const float vi = unpack_swb(M[i]);
    ming = fminf(ming, prev - vi);
    prev = vi;
  }
  ming = fminf(ming, prev - unpack_swb(r9));

  // ---- leader produces outputs (rare exact f64 redo when ambiguous) ----
  if (grow < T && q == 0) {
    float sw[TOPK]; int id8[TOPK];
#pragma unroll
    for (int i = 0; i < TOPK; ++i) {
      sw[i]  = unpack_swb(M[i]);
      id8[i] = 255 - (int)(M[i] & 255u);
    }
    if (ming < 6e-6f) {               // ~1e-3 of rows: exact rescan
      uint32_t K[TOPK], I[TOPK];
#pragma unroll
      for (int i = 0; i < TOPK; ++i) { K[i] = 0u; I[i] = 0u; }
      const float* rowp = logits + (size_t)grow * NEXP;
      for (int c = 0; c < NEXP; ++c) {
        const double sd = 1.0 / (1.0 + exp(-(double)rowp[c]));
        const float swb = (float)sd + bias[c];
        uint32_t k2 = fmap(swb); uint32_t i2 = (uint32_t)c;
#pragma unroll
        for (int s = 0; s < TOPK; ++s) {
          const bool t = k2 > K[s];
          const uint32_t ok = K[s], oi = I[s];
          K[s] = t ? k2 : ok; I[s] = t ? i2 : oi;
          k2 = t ? ok : k2; i2 = t ? oi : i2;
        }
      }
#pragma unroll
      for (int i = 0; i < TOPK; ++i) { sw[i] = funmap(K[i]); id8[i] = (int)I[i]; }
    }
    float s[TOPK]; float sum = 0.f;
#pragma unroll
    for (int i = 0; i < TOPK; ++i) { s[i] = sw[i] - bias[id8[i]]; sum += s[i]; }
    const float innv = 1.0f / (sum + 1e-20f);
    float* const po = out_idx + (size_t)grow * 8;
    float* const pw = out_w   + (size_t)grow * 8;
    *(float4*)(po)     = make_float4((float)id8[0], (float)id8[1], (float)id8[2], (float)id8[3]);
    *(float4*)(po + 4) = make_float4((float)id8[4], (float)id8[5], (float)id8[6], (float)id8[7]);
    *(float4*)(pw)     = make_float4(s[0]*innv, s[1]*innv, s[2]*innv, s[3]*innv);
    *(float4*)(pw + 4) = make_float4(s[4]*innv, s[5]*innv, s[6]*innv, s[7]*innv);
  }
}

extern "C" void kernel_launch(void* const* d_in, const int* in_sizes, int n_in,
                              void* d_out, int out_size, void* d_ws, size_t ws_size,
                              hipStream_t stream) {
  const float* logits = (const float*)d_in[0];
  const float* bias   = (const float*)d_in[1];
  const int T = in_sizes[0] / NEXP;
  float* out     = (float*)d_out;
  float* out_idx = out;
  float* out_w   = out + (size_t)T * TOPK;
  const int blocks = (T + 63) / 64;
  moe_route_kernel<<<blocks, 256, 0, stream>>>(logits, bias, out_idx, out_w, T);
}

// Round 8
// 208.361 us; speedup vs baseline: 1.4410x; 1.4129x over previous
//
#include <hip/hip_runtime.h>
#include <math.h>
#include <stdint.h>
#include <utility>

#define TOPK 8
#define NEXP 256
#define DEPTH 4   // DMAs in flight per wave
#define NSLOT 5   // ring slots = DEPTH+1: in-flight DMAs never alias the read slot

// ---------- compile-time for ----------
template <typename F, int... Is>
__device__ __forceinline__ void static_for_impl(F&& f, std::integer_sequence<int, Is...>) {
  int dummy[] = {0, ((void)f(std::integral_constant<int, Is>{}), 0)...};
  (void)dummy;
}
template <int N, typename F>
__device__ __forceinline__ void static_for(F&& f) {
  static_for_impl((F&&)f, std::make_integer_sequence<int, N>{});
}

// ---------- exact-path helpers ----------
__device__ __forceinline__ uint32_t fmap(float v) {
  uint32_t b = __float_as_uint(v);
  uint32_t m = (uint32_t)((int32_t)b >> 31) | 0x80000000u;
  return b ^ m;
}
__device__ __forceinline__ float funmap(uint32_t k) {
  uint32_t b = (k & 0x80000000u) ? (k ^ 0x80000000u) : ~k;
  return __uint_as_float(b);
}
// larger key wins; equal keys -> smaller index wins (jax tie-break)
__device__ __forceinline__ bool gtr(uint32_t ka, uint32_t ia, uint32_t kb, uint32_t ib) {
  return (ka > kb) || (ka == kb && ia < ib);
}

// ---------- fast-path fixed-point packed keys (proven R4/R7) ----------
__device__ __forceinline__ float unpack_swb(uint32_t p) {
  return fmaf((float)(p >> 8), 9.5367431640625e-07f, -8.0f);
}

#define PINSERT(Karr, pp)                               \
  { uint32_t _c = (pp);                                 \
    _Pragma("unroll")                                   \
    for (int _s = 0; _s < TOPK; ++_s) {                 \
      const uint32_t _o = Karr[_s];                     \
      const uint32_t _hi = _o > _c ? _o : _c;           \
      const uint32_t _lo = _o > _c ? _c : _o;           \
      Karr[_s] = _hi; _c = _lo;                         \
    }                                                   \
    r9 = r9 > _c ? r9 : _c; }

#define PKEY(sv, bv, ci)                                                  \
  ({ const float _e = __expf(-(sv));                                      \
     const float _iv = __builtin_amdgcn_rcpf(1.0f + _e);                  \
     const float _swb = _iv + (bv);                                       \
     const uint32_t _u = (uint32_t)fmaf(_swb, 1048576.0f, 8388608.0f);    \
     (_u << 8) | (uint32_t)(255 - (ci)); })

#define CE(i, j) { const uint32_t _a = M[i], _b = M[j];                   \
                   M[i] = _a > _b ? _a : _b; M[j] = _a > _b ? _b : _a; }
#define SORT8_BITONIC()                                                   \
  CE(0,4) CE(1,5) CE(2,6) CE(3,7)                                         \
  CE(0,2) CE(1,3) CE(4,6) CE(5,7)                                         \
  CE(0,1) CE(2,3) CE(4,5) CE(6,7)

// keyed compare-exchange (descending) with index tie-break
#define CEI(a, b)                                                         \
  { const bool _g = gtr(M[a], MI[a], M[b], MI[b]);                        \
    const uint32_t _k1 = _g ? M[a] : M[b], _k2 = _g ? M[b] : M[a];        \
    const uint32_t _i1 = _g ? MI[a] : MI[b], _i2 = _g ? MI[b] : MI[a];    \
    M[a] = _k1; M[b] = _k2; MI[a] = _i1; MI[b] = _i2; }

__device__ __forceinline__ void prefetch_lds(const char* g, char* l) {
  __builtin_amdgcn_global_load_lds(
      (const __attribute__((address_space(1))) void*)g,
      (__attribute__((address_space(3))) void*)l, 16, 0, 0);
}

// exact f64 redo of one row on one lane (safety path only)
__device__ __forceinline__ void exact_redo_row(const float* __restrict__ rowp,
                                               const float* __restrict__ bias,
                                               float* sw, int* id8) {
  uint32_t K[TOPK], I[TOPK];
#pragma unroll
  for (int i = 0; i < TOPK; ++i) { K[i] = 0u; I[i] = 0u; }
  for (int c = 0; c < NEXP; ++c) {
    const double sd = 1.0 / (1.0 + exp(-(double)rowp[c]));
    const float swb = (float)sd + bias[c];
    uint32_t k2 = fmap(swb); uint32_t i2 = (uint32_t)c;
#pragma unroll
    for (int s = 0; s < TOPK; ++s) {
      const bool t = k2 > K[s];
      const uint32_t ok = K[s], oi = I[s];
      K[s] = t ? k2 : ok; I[s] = t ? i2 : oi;
      k2 = t ? ok : k2; i2 = t ? oi : i2;
    }
  }
#pragma unroll
  for (int i = 0; i < TOPK; ++i) { sw[i] = funmap(K[i]); id8[i] = (int)I[i]; }
}

__global__ __launch_bounds__(256, 8)
void moe_route_kernel(const float* __restrict__ logits,
                      const float* __restrict__ bias,
                      float* __restrict__ out_idx,
                      float* __restrict__ out_w,
                      int T, unsigned int* __restrict__ wl, int cap, int use_ws)
{
  __shared__ float biasLDS[NEXP];            // 1KB
  __shared__ char  ring[4][NSLOT * 1024];    // 20KB: private 5KB ring per wave

  const int tid  = threadIdx.x;
  const int lane = tid & 63;
  const int wave = tid >> 6;
  const int q    = lane & 3;                      // 4 lanes per row
  const int grow = blockIdx.x * 64 + (tid >> 2);
  const int rrow = grow < T ? grow : (T - 1);

  if (tid < NEXP) biasLDS[tid] = bias[tid];
  __syncthreads();

  const char* gbase = (const char*)(logits + (size_t)rrow * NEXP) + q * 16;
  char* ringw = ring[wave];

#pragma unroll
  for (int k = 0; k < DEPTH; ++k)
    prefetch_lds(gbase + (size_t)k * 64, ringw + (k % NSLOT) * 1024);

  uint32_t A[TOPK], B[TOPK];
#pragma unroll
  for (int i = 0; i < TOPK; ++i) { A[i] = 0u; B[i] = 0u; }
  uint32_t r9 = 0u;

  static_for<16>([&](auto kc) {
    constexpr int k = decltype(kc)::value;
    if (k + DEPTH < 16)
      prefetch_lds(gbase + (size_t)(k + DEPTH) * 64,
                   ringw + ((k + DEPTH) % NSLOT) * 1024);
    constexpr int nwait = (k + DEPTH < 16) ? DEPTH : (15 - k);
    __builtin_amdgcn_s_waitcnt(0x0F70 | nwait);  // vmcnt(nwait) only

    const float4 x  = *(const float4*)(ringw + (k % NSLOT) * 1024 + lane * 16);
    const float4 bb = ((const float4*)biasLDS)[q + 4 * k];
    const int cb = 4 * q + 16 * k;
    const uint32_t p0 = PKEY(x.x, bb.x, cb + 0);
    const uint32_t p1 = PKEY(x.y, bb.y, cb + 1);
    const uint32_t p2 = PKEY(x.z, bb.z, cb + 2);
    const uint32_t p3 = PKEY(x.w, bb.w, cb + 3);
    PINSERT(A, p0); PINSERT(B, p1);
    PINSERT(A, p2); PINSERT(B, p3);
  });

  uint32_t M[TOPK];
  {
    uint32_t dmax = 0u;
#pragma unroll
    for (int i = 0; i < TOPK; ++i) {
      const uint32_t a = A[i], b = B[TOPK - 1 - i];
      M[i] = a > b ? a : b;
      const uint32_t d = a > b ? b : a;
      dmax = dmax > d ? dmax : d;
    }
    r9 = r9 > dmax ? r9 : dmax;
    SORT8_BITONIC()
  }

#pragma unroll
  for (int mstep = 0; mstep < 2; ++mstep) {
    const int mask = 1 << mstep;
    uint32_t P[TOPK];
#pragma unroll
    for (int i = 0; i < TOPK; ++i)
      P[i] = (uint32_t)__shfl_xor((int)M[i], mask, 64);
    const uint32_t r9p = (uint32_t)__shfl_xor((int)r9, mask, 64);
    r9 = r9 > r9p ? r9 : r9p;
    uint32_t dmax = 0u;
#pragma unroll
    for (int i = 0; i < TOPK; ++i) {
      const uint32_t a = M[i], b = P[TOPK - 1 - i];
      const uint32_t hi = a > b ? a : b;
      const uint32_t d  = a > b ? b : a;
      M[i] = hi;
      dmax = dmax > d ? dmax : d;
    }
    r9 = r9 > dmax ? r9 : dmax;
    SORT8_BITONIC()
  }

  float prev = unpack_swb(M[0]);
  float ming = 1e30f;
#pragma unroll
  for (int i = 1; i < TOPK; ++i) {
    const float vi = unpack_swb(M[i]);
    ming = fminf(ming, prev - vi);
    prev = vi;
  }
  ming = fminf(ming, prev - unpack_swb(r9));

  if (grow < T && q == 0) {
    float sw[TOPK]; int id8[TOPK];
#pragma unroll
    for (int i = 0; i < TOPK; ++i) {
      sw[i]  = unpack_swb(M[i]);
      id8[i] = 255 - (int)(M[i] & 255u);
    }
    if (ming < 6e-6f) {               // ~1e-3 of rows: ambiguous
      bool deferred = false;
      if (use_ws) {
        const int pos = (int)atomicAdd(wl, 1u);
        if (pos < cap) { wl[1 + pos] = (unsigned int)grow; deferred = true; }
      }
      if (!deferred)                   // safety: inline exact redo
        exact_redo_row(logits + (size_t)grow * NEXP, bias, sw, id8);
      // if deferred: write fast-path guess; fix-kernel overwrites later
    }
    float s[TOPK]; float sum = 0.f;
#pragma unroll
    for (int i = 0; i < TOPK; ++i) { s[i] = sw[i] - bias[id8[i]]; sum += s[i]; }
    const float innv = 1.0f / (sum + 1e-20f);
    float* const po = out_idx + (size_t)grow * 8;
    float* const pw = out_w   + (size_t)grow * 8;
    *(float4*)(po)     = make_float4((float)id8[0], (float)id8[1], (float)id8[2], (float)id8[3]);
    *(float4*)(po + 4) = make_float4((float)id8[4], (float)id8[5], (float)id8[6], (float)id8[7]);
    *(float4*)(pw)     = make_float4(s[0]*innv, s[1]*innv, s[2]*innv, s[3]*innv);
    *(float4*)(pw + 4) = make_float4(s[4]*innv, s[5]*innv, s[6]*innv, s[7]*innv);
  }
}

// wave-parallel exact f64 redo of flagged rows: 64 lanes x 4 elems each
__global__ __launch_bounds__(256, 4)
void moe_fix_kernel(const float* __restrict__ logits,
                    const float* __restrict__ bias,
                    float* __restrict__ out_idx,
                    float* __restrict__ out_w,
                    const unsigned int* __restrict__ wl, int cap)
{
  const int lane   = threadIdx.x & 63;
  const int waveId = (blockIdx.x << 2) | (threadIdx.x >> 6);
  int count = (int)wl[0]; if (count > cap) count = cap;

  for (int wi = waveId; wi < count; wi += 256) {
    const int row = (int)wl[1 + wi];
    const float* rowp = logits + (size_t)row * NEXP;
    uint32_t M[TOPK], MI[TOPK];
#pragma unroll
    for (int i = 0; i < TOPK; ++i) { M[i] = 0u; MI[i] = 0u; }
    // lane owns c = lane + 64j, ascending j -> within-lane ties keep smaller idx
#pragma unroll
    for (int j = 0; j < 4; ++j) {
      const int c = lane + (j << 6);
      const double sd = 1.0 / (1.0 + exp(-(double)rowp[c]));
      const float swb = (float)sd + bias[c];
      uint32_t k2 = fmap(swb); uint32_t i2 = (uint32_t)c;
#pragma unroll
      for (int s = 0; s < TOPK; ++s) {
        const bool t = k2 > M[s];
        const uint32_t ok = M[s], oi = MI[s];
        M[s] = t ? k2 : ok; MI[s] = t ? i2 : oi;
        k2 = t ? ok : k2; i2 = t ? oi : i2;
      }
    }
    // 6-step xor merge across the full wave (result replicated)
#pragma unroll
    for (int mstep = 0; mstep < 6; ++mstep) {
      const int mask = 1 << mstep;
      uint32_t P[TOPK], Q[TOPK];
#pragma unroll
      for (int i = 0; i < TOPK; ++i) {
        P[i] = (uint32_t)__shfl_xor((int)M[i], mask, 64);
        Q[i] = (uint32_t)__shfl_xor((int)MI[i], mask, 64);
      }
#pragma unroll
      for (int i = 0; i < TOPK; ++i) {
        const uint32_t kb = P[TOPK - 1 - i], ib = Q[TOPK - 1 - i];
        const bool g = gtr(M[i], MI[i], kb, ib);
        M[i]  = g ? M[i]  : kb;
        MI[i] = g ? MI[i] : ib;
      }
      CEI(0,4) CEI(1,5) CEI(2,6) CEI(3,7)
      CEI(0,2) CEI(1,3) CEI(4,6) CEI(5,7)
      CEI(0,1) CEI(2,3) CEI(4,5) CEI(6,7)
    }
    if (lane == 0) {
      float s[TOPK]; float sum = 0.f;
#pragma unroll
      for (int i = 0; i < TOPK; ++i) {
        s[i] = funmap(M[i]) - bias[MI[i]];
        sum += s[i];
      }
      const float innv = 1.0f / (sum + 1e-20f);
      float* const po = out_idx + (size_t)row * 8;
      float* const pw = out_w   + (size_t)row * 8;
      *(float4*)(po)     = make_float4((float)MI[0], (float)MI[1], (float)MI[2], (float)MI[3]);
      *(float4*)(po + 4) = make_float4((float)MI[4], (float)MI[5], (float)MI[6], (float)MI[7]);
      *(float4*)(pw)     = make_float4(s[0]*innv, s[1]*innv, s[2]*innv, s[3]*innv);
      *(float4*)(pw + 4) = make_float4(s[4]*innv, s[5]*innv, s[6]*innv, s[7]*innv);
    }
  }
}

extern "C" void kernel_launch(void* const* d_in, const int* in_sizes, int n_in,
                              void* d_out, int out_size, void* d_ws, size_t ws_size,
                              hipStream_t stream) {
  const float* logits = (const float*)d_in[0];
  const float* bias   = (const float*)d_in[1];
  const int T = in_sizes[0] / NEXP;
  float* out     = (float*)d_out;
  float* out_idx = out;
  float* out_w   = out + (size_t)T * TOPK;
  const int blocks = (T + 63) / 64;

  unsigned int* wl = (unsigned int*)d_ws;
  int cap = (ws_size > 4) ? (int)((ws_size - 4) / 4) : 0;
  if (cap > 65536) cap = 65536;
  const int use_ws = (cap >= 4096) ? 1 : 0;   // constant per session: graph-safe

  if (use_ws) hipMemsetAsync(d_ws, 0, 4, stream);
  moe_route_kernel<<<blocks, 256, 0, stream>>>(logits, bias, out_idx, out_w, T,
                                               wl, cap, use_ws);
  if (use_ws) moe_fix_kernel<<<64, 256, 0, stream>>>(logits, bias, out_idx, out_w,
                                                     wl, cap);
}